// Round 1
// baseline (160.858 us; speedup 1.0000x reference)
//
#include <hip/hip_runtime.h>

#define NN   2048
#define F0D  128
#define HIDD 64
#define OUTD 16
#define KDEG 10

// ws float layout:
//   [0]    buf0 (2048)
//   [2048] buf1 (2048)
//   [4096] buf2 (2048)
//   [6144] w    (2048)
//   [8192] c    (16)
//   [8208] Hg   (512)

__global__ void k_init(const float* __restrict__ theta, float* __restrict__ ws) {
    float* buf0 = ws;
    float* buf1 = ws + 2048;
    float* w    = ws + 6144;
    float* c    = ws + 8192;
    float* Hg   = ws + 8208;
    int t = blockIdx.x * 256 + threadIdx.x;   // grid 8 x 256 = 2048
    if (t < 2048) { buf0[t] = 1.0f; buf1[t] = 0.0f; w[t] = 0.0f; }
    if (t < 512) Hg[t] = 0.0f;
    if (t < 16) {
        int j = t;
        if (j <= KDEG) {
            const float C10[11] = {1,10,45,120,210,252,210,120,45,10,1};
            float acc = 0.f;
            for (int i = 0; i <= j; ++i) {
                int n = KDEG - i, r = j - i;
                long long cm = 1;
                for (int s = 1; s <= r; ++s) cm = cm * (n - r + s) / s;  // exact
                float term = theta[i] * C10[i] * (float)cm;
                if ((j - i) & 1) term = -term;
                acc += term;
            }
            c[j] = acc;
        } else {
            c[j] = 0.f;
        }
    }
}

// y = L^T x  (y[u] = sum_v L[v,u] x[v]); also: vchunk==0 blocks zero zbuf,
// vchunk==1 blocks accumulate w += c[jm1] * x.
__global__ __launch_bounds__(256) void k_matvec(const float* __restrict__ L,
                                                const float* __restrict__ x,
                                                float* __restrict__ y,
                                                float* __restrict__ zbuf,
                                                float* __restrict__ w,
                                                const float* __restrict__ c,
                                                int jm1) {
    // grid dim3(32, 8): blockIdx.x = utile (64 u each), blockIdx.y = vchunk (256 v each)
    int t = threadIdx.x;
    if (blockIdx.y == 0) {
        if (t < 64) zbuf[blockIdx.x * 64 + t] = 0.f;
    } else if (blockIdx.y == 1) {
        if (t < 64) { int u = blockIdx.x * 64 + t; w[u] += c[jm1] * x[u]; }
    }
    int ugrp  = t & 15;            // 16 groups of 4 consecutive u (float4)
    int wv    = t >> 6;            // wave 0..3
    int vlane = (t >> 4) & 3;      // 4 v-streams per wave
    int vstream = wv * 4 + vlane;  // 0..15
    int v0 = blockIdx.y * 256;
    const float4* Lp = (const float4*)L;
    int col = blockIdx.x * 16 + ugrp;   // float4 column index (u0/4)
    float4 acc = make_float4(0.f, 0.f, 0.f, 0.f);
    #pragma unroll
    for (int it = 0; it < 16; ++it) {
        int v = v0 + vstream + 16 * it;
        float xv = x[v];
        float4 lv = Lp[(size_t)v * (NN / 4) + col];
        acc.x += lv.x * xv; acc.y += lv.y * xv;
        acc.z += lv.z * xv; acc.w += lv.w * xv;
    }
    // reduce over the 4 v-streams within the wave (lanes 16 apart)
    acc.x += __shfl_xor(acc.x, 16); acc.y += __shfl_xor(acc.y, 16);
    acc.z += __shfl_xor(acc.z, 16); acc.w += __shfl_xor(acc.w, 16);
    acc.x += __shfl_xor(acc.x, 32); acc.y += __shfl_xor(acc.y, 32);
    acc.z += __shfl_xor(acc.z, 32); acc.w += __shfl_xor(acc.w, 32);
    if (((t >> 4) & 3) == 0) {
        int u0 = blockIdx.x * 64 + ugrp * 4;
        atomicAdd(&y[u0 + 0], acc.x);
        atomicAdd(&y[u0 + 1], acc.y);
        atomicAdd(&y[u0 + 2], acc.z);
        atomicAdd(&y[u0 + 3], acc.w);
    }
}

// Hg[b,h] += (1/N) * sum_{v in chunk} weff[v] * relu(X[b,v,:] @ W1[:,h] + b1[h])
// weff[v] = w[v] + c[K] * pK[v]
__global__ __launch_bounds__(256) void k_head(const float* __restrict__ X,
                                              const float* __restrict__ W1,
                                              const float* __restrict__ b1,
                                              const float* __restrict__ w,
                                              const float* __restrict__ pK,
                                              const float* __restrict__ c,
                                              float* __restrict__ Hg) {
    // grid dim3(32, 8): x = vchunk (64 v each), y = b
    __shared__ __align__(16) float W1t[64][132];   // transposed W1, padded row stride
    __shared__ float redm[16][65];
    int t = threadIdx.x;
    for (int i = t; i < F0D * HIDD; i += 256) {
        int f = i >> 6, h = i & 63;
        W1t[h][f] = W1[i];
    }
    __syncthreads();
    int b = blockIdx.y;
    int vchunk = blockIdx.x;
    int hg = t & 15;          // thread h's: hg + 16*j, j=0..3
    int vg = t >> 4;          // 16 v-groups of 4 rows
    int vbase = vchunk * 64 + vg * 4;
    const float* Xb = X + ((size_t)b * NN + vbase) * F0D;
    float acc[4][4] = {};
    for (int f = 0; f < F0D; f += 4) {
        float4 xr[4];
        #pragma unroll
        for (int i = 0; i < 4; ++i)
            xr[i] = *(const float4*)(Xb + (size_t)i * F0D + f);
        #pragma unroll
        for (int j = 0; j < 4; ++j) {
            float4 wr = *(const float4*)(&W1t[hg + 16 * j][f]);
            #pragma unroll
            for (int i = 0; i < 4; ++i) {
                acc[i][j] += xr[i].x * wr.x + xr[i].y * wr.y
                           + xr[i].z * wr.z + xr[i].w * wr.w;
            }
        }
    }
    float cK = c[KDEG];
    float hsum[4] = {0.f, 0.f, 0.f, 0.f};
    #pragma unroll
    for (int i = 0; i < 4; ++i) {
        int v = vbase + i;
        float weff = w[v] + cK * pK[v];
        #pragma unroll
        for (int j = 0; j < 4; ++j) {
            float r = acc[i][j] + b1[hg + 16 * j];
            r = r > 0.f ? r : 0.f;
            hsum[j] += r * weff;
        }
    }
    #pragma unroll
    for (int j = 0; j < 4; ++j) redm[vg][hg + 16 * j] = hsum[j];
    __syncthreads();
    if (t < 64) {
        float s = 0.f;
        #pragma unroll
        for (int i = 0; i < 16; ++i) s += redm[i][t];
        atomicAdd(&Hg[b * 64 + t], s * (1.0f / (float)NN));
    }
}

__global__ void k_out(const float* __restrict__ Hg, const float* __restrict__ W2,
                      const float* __restrict__ b2, float* __restrict__ out) {
    int t = threadIdx.x;            // 128 threads
    int o = t & 15, b = t >> 4;
    float acc = b2[o];
    #pragma unroll
    for (int h = 0; h < HIDD; ++h) acc += Hg[b * 64 + h] * W2[h * 16 + o];
    out[b * 16 + o] = acc;
}

extern "C" void kernel_launch(void* const* d_in, const int* in_sizes, int n_in,
                              void* d_out, int out_size, void* d_ws, size_t ws_size,
                              hipStream_t stream) {
    const float* X     = (const float*)d_in[0];
    const float* L     = (const float*)d_in[1];
    const float* W1    = (const float*)d_in[2];
    const float* b1    = (const float*)d_in[3];
    const float* W2    = (const float*)d_in[4];
    const float* b2    = (const float*)d_in[5];
    const float* theta = (const float*)d_in[6];
    // d_in[7] = dp = 0 -> dropout is identity; ignored.

    float* ws   = (float*)d_ws;
    float* buf[3] = {ws, ws + 2048, ws + 4096};
    float* w    = ws + 6144;
    float* c    = ws + 8192;
    float* Hg   = ws + 8208;

    k_init<<<8, 256, 0, stream>>>(theta, ws);

    for (int j = 1; j <= KDEG; ++j) {
        k_matvec<<<dim3(32, 8), 256, 0, stream>>>(
            L, buf[(j - 1) % 3], buf[j % 3], buf[(j + 1) % 3], w, c, j - 1);
    }
    // p_K ends in buf[KDEG % 3] = buf1
    k_head<<<dim3(32, 8), 256, 0, stream>>>(X, W1, b1, w, buf[KDEG % 3], c, Hg);
    k_out<<<1, 128, 0, stream>>>(Hg, W2, b2, (float*)d_out);
}